// Round 2
// baseline (3387.420 us; speedup 1.0000x reference)
//
#include <hip/hip_runtime.h>

constexpr int NN = 120000;
constexpr int EE = 1200000;
constexpr float EPSV = 1e-5f;

__global__ __launch_bounds__(256) void k_count_deg(const int* __restrict__ dst, float* __restrict__ deg){
  int e = blockIdx.x*256 + threadIdx.x;
  if (e < EE) atomicAdd(&deg[dst[e]], 1.0f);
}

// encode: deg[n] = 1/cnt if cnt>0 else -1.0  (sign bit = "no neighbors" flag)
__global__ __launch_bounds__(256) void k_finalize_deg(float* deg){
  int n = blockIdx.x*256 + threadIdx.x;
  if (n < NN){
    float c = deg[n];
    deg[n] = (c > 0.0f) ? (1.0f/c) : -1.0f;
  }
}

// one edge per 64 lanes: lane f adds x[src][f] into agg[dst][f]
__global__ __launch_bounds__(256) void k_scatter64(const float* __restrict__ x, const int* __restrict__ src,
                                                   const int* __restrict__ dst, float* __restrict__ agg){
  unsigned long long idx = (unsigned long long)blockIdx.x*256ull + threadIdx.x;
  int e = (int)(idx >> 6);
  int f = (int)(idx & 63);
  int s = src[e], d = dst[e];
  atomicAdd(&agg[(size_t)d*64 + f], x[(size_t)s*64 + f]);
}

__global__ __launch_bounds__(256) void k_scatter14(const float* __restrict__ x, const int* __restrict__ src,
                                                   const int* __restrict__ dst, float* __restrict__ agg){
  int e = blockIdx.x*256 + threadIdx.x;
  if (e >= EE) return;
  int s = src[e], d = dst[e];
  #pragma unroll
  for (int f=0; f<14; f++)
    atomicAdd(&agg[(size_t)d*14 + f], x[(size_t)s*14 + f]);
}

// Fold BN affine (scale a, shift s0 from stats of the PREVIOUS layer's raw activated output)
// into weights. wbuf layout: Wn'(din*64) | Wr'(din*64) | b_base(64) | b_agg(64)
//   Wn' = diag(a)Wn, Wr' = diag(a)Wr
//   b_base = b + s0@Wr  (always applied)
//   b_agg  = s0@Wn      (applied only for nodes WITH neighbors — mean of empty set is 0)
__global__ __launch_bounds__(256) void k_prep(const float* __restrict__ Wn, const float* __restrict__ Wr,
                                              const float* __restrict__ b, const float* __restrict__ stats,
                                              const float* __restrict__ g, const float* __restrict__ be,
                                              float* __restrict__ wbuf, int din){
  __shared__ float sc[64], sh[64];
  int t = threadIdx.x;
  if (t < 64){
    float a = 1.0f, s0 = 0.0f;
    if (stats){
      float m = stats[t] * (1.0f/NN);
      float v = stats[64+t] * (1.0f/NN) - m*m;
      a  = g[t] * rsqrtf(v + EPSV);
      s0 = be[t] - m*a;
    }
    sc[t] = a; sh[t] = s0;
  }
  __syncthreads();
  for (int i = t; i < din*64; i += 256){
    int k = i >> 6;
    wbuf[i]          = sc[k]*Wn[i];
    wbuf[din*64 + i] = sc[k]*Wr[i];
  }
  if (t < 64){
    float accB = b ? b[t] : 0.0f;
    float accN = 0.0f;
    for (int k=0;k<din;k++){
      accB += sh[k]*Wr[k*64+t];
      accN += sh[k]*Wn[k*64+t];
    }
    wbuf[2*din*64 + t]      = accB;
    wbuf[2*din*64 + 64 + t] = accN;
  }
}

// out[n][j] = 1{deg>0}*( invdeg[n]*(agg[n]@Wn')[j] + b_agg[j] ) + (x[n]@Wr')[j] + b_base[j]
// then activation, optional BN-stats accumulation.
// One wave per node; lane j holds W' columns in registers; node rows loaded as wave-uniform float4s.
template<int DIN, int ACT, bool STATS>
__global__ __launch_bounds__(256) void k_gemm_conv(const float* __restrict__ agg, const float* __restrict__ x,
                                                   const float* __restrict__ invdeg, const float* __restrict__ wbuf,
                                                   float* __restrict__ out, float* __restrict__ stats){
  const int lane  = threadIdx.x & 63;
  const int wave  = blockIdx.x*4 + (threadIdx.x >> 6);
  const int nwav  = gridDim.x*4;
  float wn[DIN], wr[DIN];
  #pragma unroll
  for (int k=0;k<DIN;k++){
    wn[k] = wbuf[k*64+lane];
    wr[k] = wbuf[(DIN+k)*64+lane];
  }
  const float bj0 = wbuf[2*DIN*64+lane];       // base bias
  const float bj1 = wbuf[2*DIN*64+64+lane];    // aggregation-shift bias (only if deg>0)
  float ls = 0.0f, lss = 0.0f;
  for (int n = wave; n < NN; n += nwav){
    const float* ar = agg + (size_t)n*DIN;
    const float* xr = x   + (size_t)n*DIN;
    float accA = 0.0f, accX = 0.0f;
    if constexpr ((DIN & 3) == 0){
      const float4* a4 = (const float4*)ar;
      const float4* x4 = (const float4*)xr;
      #pragma unroll
      for (int c=0;c<DIN/4;c++){
        float4 a = a4[c], b = x4[c];
        accA = fmaf(a.x, wn[4*c+0], accA);
        accX = fmaf(b.x, wr[4*c+0], accX);
        accA = fmaf(a.y, wn[4*c+1], accA);
        accX = fmaf(b.y, wr[4*c+1], accX);
        accA = fmaf(a.z, wn[4*c+2], accA);
        accX = fmaf(b.z, wr[4*c+2], accX);
        accA = fmaf(a.w, wn[4*c+3], accA);
        accX = fmaf(b.w, wr[4*c+3], accX);
      }
    } else {
      #pragma unroll
      for (int k=0;k<DIN;k++){
        accA = fmaf(ar[k], wn[k], accA);
        accX = fmaf(xr[k], wr[k], accX);
      }
    }
    float iv = invdeg[n];                       // negative => no neighbors
    float aggterm = (iv > 0.0f) ? fmaf(accA, iv, bj1) : 0.0f;
    float z = accX + bj0 + aggterm;
    if (ACT == 1) z = z > 0.0f ? z : 0.01f*z;
    if (ACT == 2) z = fmaxf(z, 0.0f);
    out[(size_t)n*64 + lane] = z;
    if (STATS){ ls += z; lss = fmaf(z,z,lss); }
  }
  if (STATS){
    atomicAdd(&stats[lane], ls);
    atomicAdd(&stats[64+lane], lss);
  }
}

// out = x @ W (+bias). DIN fixed 64. Optional stats accumulation (raw pre-BN values).
template<int DOUT, bool STATS, bool BIAS>
__global__ __launch_bounds__(256) void k_gemm_lin(const float* __restrict__ x, const float* __restrict__ W,
                                                  const float* __restrict__ bias, float* __restrict__ out,
                                                  float* __restrict__ stats){
  const int lane = threadIdx.x & 63;
  const int wave = blockIdx.x*4 + (threadIdx.x >> 6);
  const int nwav = gridDim.x*4;
  if (DOUT < 64 && lane >= DOUT) return;
  float w[64];
  #pragma unroll
  for (int k=0;k<64;k++) w[k] = W[k*DOUT + lane];
  const float bj = BIAS ? bias[lane] : 0.0f;
  float ls = 0.0f, lss = 0.0f;
  for (int n = wave; n < NN; n += nwav){
    const float4* x4 = (const float4*)(x + (size_t)n*64);
    float acc0 = 0.0f, acc1 = 0.0f;
    #pragma unroll
    for (int c=0;c<8;c++){
      float4 v0 = x4[2*c], v1 = x4[2*c+1];
      acc0 = fmaf(v0.x, w[8*c+0], acc0);
      acc1 = fmaf(v1.x, w[8*c+4], acc1);
      acc0 = fmaf(v0.y, w[8*c+1], acc0);
      acc1 = fmaf(v1.y, w[8*c+5], acc1);
      acc0 = fmaf(v0.z, w[8*c+2], acc0);
      acc1 = fmaf(v1.z, w[8*c+6], acc1);
      acc0 = fmaf(v0.w, w[8*c+3], acc0);
      acc1 = fmaf(v1.w, w[8*c+7], acc1);
    }
    float z = acc0 + acc1 + bj;
    out[(size_t)n*DOUT + lane] = z;
    if (STATS){ ls += z; lss = fmaf(z,z,lss); }
  }
  if (STATS){ atomicAdd(&stats[lane], ls); atomicAdd(&stats[64+lane], lss); }
}

// h = relu(bn(h)) elementwise
__global__ __launch_bounds__(256) void k_normrelu(float* __restrict__ h, const float* __restrict__ stats,
                                                  const float* __restrict__ g, const float* __restrict__ be){
  size_t idx = (size_t)blockIdx.x*256 + threadIdx.x;
  int f = (int)(idx & 63);
  float m = stats[f] * (1.0f/NN);
  float v = stats[64+f] * (1.0f/NN) - m*m;
  float a = g[f]*rsqrtf(v+EPSV);
  float b = be[f] - m*a;
  float z = h[idx];
  h[idx] = fmaxf(fmaf(a, z, b), 0.0f);
}

extern "C" void kernel_launch(void* const* d_in, const int* in_sizes, int n_in,
                              void* d_out, int out_size, void* d_ws, size_t ws_size,
                              hipStream_t stream){
  const float* x1  = (const float*)d_in[0];
  const int*   ei  = (const int*)d_in[1];
  const int* srcp = ei;
  const int* dstp = ei + EE;
  const float *Wn1=(const float*)d_in[2],  *Wr1=(const float*)d_in[3],  *b1=(const float*)d_in[4];
  const float *Wn2=(const float*)d_in[5],  *Wr2=(const float*)d_in[6],  *b2=(const float*)d_in[7];
  const float *Wn3=(const float*)d_in[8],  *Wr3=(const float*)d_in[9],  *b3=(const float*)d_in[10];
  const float *Wn4=(const float*)d_in[11], *Wr4=(const float*)d_in[12], *b4=(const float*)d_in[13];
  const float *g1=(const float*)d_in[14], *be1=(const float*)d_in[15];
  const float *g2=(const float*)d_in[16], *be2=(const float*)d_in[17];
  const float *g3=(const float*)d_in[18], *be3=(const float*)d_in[19];
  const float *Wm0=(const float*)d_in[20], *gm0=(const float*)d_in[21], *bem0=(const float*)d_in[22];
  const float *Wm1=(const float*)d_in[23], *gm1=(const float*)d_in[24], *bem1=(const float*)d_in[25];
  const float *Wm2=(const float*)d_in[26], *bm2=(const float*)d_in[27];
  float* out = (float*)d_out;

  char* ws = (char*)d_ws;
  float* deg   = (float*)(ws);                    // N floats -> becomes inv_deg (sign-encoded)
  float* agg   = (float*)(ws + (1ull<<20));       // N*64 floats (30.72 MB)
  float* hA    = (float*)(ws + (32ull<<20));      // N*64 floats
  float* hB    = (float*)(ws + (63ull<<20));      // N*64 floats
  float* stats = (float*)(ws + (94ull<<20));      // 5 BNs x 128 floats
  float* wbuf  = (float*)(ws + (94ull<<20) + 8192); // Wn' | Wr' | b_base | b_agg

  hipMemsetAsync(deg,   0, NN*sizeof(float), stream);
  hipMemsetAsync(stats, 0, 5*128*sizeof(float), stream);
  k_count_deg   <<<(EE+255)/256,256,0,stream>>>(dstp, deg);
  k_finalize_deg<<<(NN+255)/256,256,0,stream>>>(deg);

  // ---- conv1: aggregate x1 (d=14), lrelu, stats->S1
  hipMemsetAsync(agg, 0, (size_t)NN*14*sizeof(float), stream);
  k_scatter14<<<(EE+255)/256,256,0,stream>>>(x1, srcp, dstp, agg);
  k_prep<<<1,256,0,stream>>>(Wn1,Wr1,b1,nullptr,nullptr,nullptr,wbuf,14);
  k_gemm_conv<14,1,true><<<2048,256,0,stream>>>(agg,x1,deg,wbuf,hA,stats);

  // ---- conv2: BN1 folded into weights; aggregate raw hA
  hipMemsetAsync(agg, 0, (size_t)NN*64*sizeof(float), stream);
  k_scatter64<<<(EE*64)/256,256,0,stream>>>(hA, srcp, dstp, agg);
  k_prep<<<1,256,0,stream>>>(Wn2,Wr2,b2,stats,g1,be1,wbuf,64);
  k_gemm_conv<64,1,true><<<2048,256,0,stream>>>(agg,hA,deg,wbuf,hB,stats+128);

  // ---- conv3: BN2 folded; relu
  hipMemsetAsync(agg, 0, (size_t)NN*64*sizeof(float), stream);
  k_scatter64<<<(EE*64)/256,256,0,stream>>>(hB, srcp, dstp, agg);
  k_prep<<<1,256,0,stream>>>(Wn3,Wr3,b3,stats+128,g2,be2,wbuf,64);
  k_gemm_conv<64,2,true><<<2048,256,0,stream>>>(agg,hB,deg,wbuf,hA,stats+256);

  // ---- conv4: BN3 folded; no act, no stats
  hipMemsetAsync(agg, 0, (size_t)NN*64*sizeof(float), stream);
  k_scatter64<<<(EE*64)/256,256,0,stream>>>(hA, srcp, dstp, agg);
  k_prep<<<1,256,0,stream>>>(Wn4,Wr4,b4,stats+256,g3,be3,wbuf,64);
  k_gemm_conv<64,0,false><<<2048,256,0,stream>>>(agg,hA,deg,wbuf,hB,nullptr);

  // ---- MLP head: z0=hB@Wm0 (stats S4) -> relu(bn) -> z1@Wm1 (stats S5) -> relu(bn) -> @Wm2+bm2
  k_gemm_lin<64,true,false><<<2048,256,0,stream>>>(hB,Wm0,nullptr,hA,stats+384);
  k_normrelu<<<(NN*64)/256,256,0,stream>>>(hA,stats+384,gm0,bem0);
  k_gemm_lin<64,true,false><<<2048,256,0,stream>>>(hA,Wm1,nullptr,hB,stats+512);
  k_normrelu<<<(NN*64)/256,256,0,stream>>>(hB,stats+512,gm1,bem1);
  k_gemm_lin<21,false,true><<<2048,256,0,stream>>>(hB,Wm2,bm2,out,nullptr);
}

// Round 3
// 2044.656 us; speedup vs baseline: 1.6567x; 1.6567x over previous
//
#include <hip/hip_runtime.h>

constexpr int NN = 120000;
constexpr int EE = 1200000;
constexpr float EPSV = 1e-5f;
constexpr int NB_SCAN = (NN + 255) / 256;   // 469

// ---------------- CSR build (no float atomics anywhere) ----------------
__global__ __launch_bounds__(256) void k_count(const int* __restrict__ dst, int* __restrict__ cnt){
  int e = blockIdx.x*256 + threadIdx.x;
  if (e < EE) atomicAdd(&cnt[dst[e]], 1);
}

__global__ __launch_bounds__(256) void k_scan1(const int* __restrict__ cnt, int* __restrict__ pre,
                                               int* __restrict__ blksum){
  __shared__ int sm[256];
  int i = blockIdx.x*256 + threadIdx.x;
  int v = (i < NN) ? cnt[i] : 0;
  sm[threadIdx.x] = v; __syncthreads();
  for (int off = 1; off < 256; off <<= 1){
    int t = (threadIdx.x >= off) ? sm[threadIdx.x - off] : 0;
    __syncthreads();
    sm[threadIdx.x] += t;
    __syncthreads();
  }
  if (i < NN) pre[i] = sm[threadIdx.x] - v;          // exclusive within block
  if (threadIdx.x == 255) blksum[blockIdx.x] = sm[255];
}

__global__ __launch_bounds__(512) void k_scan2(int* __restrict__ blksum){
  __shared__ int sm[512];
  int v = (threadIdx.x < NB_SCAN) ? blksum[threadIdx.x] : 0;
  sm[threadIdx.x] = v; __syncthreads();
  for (int off = 1; off < 512; off <<= 1){
    int t = (threadIdx.x >= off) ? sm[threadIdx.x - off] : 0;
    __syncthreads();
    sm[threadIdx.x] += t;
    __syncthreads();
  }
  if (threadIdx.x < NB_SCAN) blksum[threadIdx.x] = sm[threadIdx.x] - v;  // exclusive
}

__global__ __launch_bounds__(256) void k_scan3(const int* __restrict__ pre, const int* __restrict__ blksum,
                                               const int* __restrict__ cnt,
                                               int* __restrict__ row_ptr, int* __restrict__ cursor,
                                               float* __restrict__ invdeg){
  int i = blockIdx.x*256 + threadIdx.x;
  if (i < NN){
    int r = pre[i] + blksum[blockIdx.x];
    row_ptr[i] = r; cursor[i] = r;
    int c = cnt[i];
    invdeg[i] = (c > 0) ? (1.0f/(float)c) : -1.0f;   // sign bit = "no neighbors"
  }
}

__global__ __launch_bounds__(256) void k_fill(const int* __restrict__ src, const int* __restrict__ dst,
                                              int* __restrict__ cursor, int* __restrict__ adj){
  int e = blockIdx.x*256 + threadIdx.x;
  if (e < EE){
    int p = atomicAdd(&cursor[dst[e]], 1);
    adj[p] = src[e];
  }
}

// ---------------- Aggregation: gather by destination ----------------
// one wave per node; lane = feature; neighbor rows are coalesced 256B reads
__global__ __launch_bounds__(256) void k_gather64(const float* __restrict__ x, const int* __restrict__ row_ptr,
                                                  const int* __restrict__ cnt, const int* __restrict__ adj,
                                                  float* __restrict__ agg){
  const int lane = threadIdx.x & 63;
  const int wave = blockIdx.x*4 + (threadIdx.x >> 6);
  const int nwav = gridDim.x*4;
  for (int n = wave; n < NN; n += nwav){
    int st = row_ptr[n], d = cnt[n];
    float acc = 0.0f;
    int j = 0;
    for (; j + 1 < d; j += 2){
      int s0 = adj[st+j], s1 = adj[st+j+1];
      float v0 = x[(size_t)s0*64 + lane];
      float v1 = x[(size_t)s1*64 + lane];
      acc += v0 + v1;
    }
    if (j < d){
      int s0 = adj[st+j];
      acc += x[(size_t)s0*64 + lane];
    }
    agg[(size_t)n*64 + lane] = acc;
  }
}

// 4 edges in parallel per wave (16-lane groups), features in lanes f<14, shuffle-reduce groups
__global__ __launch_bounds__(256) void k_gather14(const float* __restrict__ x, const int* __restrict__ row_ptr,
                                                  const int* __restrict__ cnt, const int* __restrict__ adj,
                                                  float* __restrict__ agg){
  const int lane = threadIdx.x & 63;
  const int f = lane & 15, g = lane >> 4;
  const int wave = blockIdx.x*4 + (threadIdx.x >> 6);
  const int nwav = gridDim.x*4;
  for (int n = wave; n < NN; n += nwav){
    int st = row_ptr[n], d = cnt[n];
    float acc = 0.0f;
    for (int j = g; j < d; j += 4){
      int s = adj[st+j];
      if (f < 14) acc += x[(size_t)s*14 + f];
    }
    acc += __shfl_down(acc, 32);
    acc += __shfl_down(acc, 16);
    if (lane < 14) agg[(size_t)n*14 + lane] = acc;
  }
}

// ---------------- BN-fold weight prep ----------------
// wbuf: Wn'(din*64) | Wr'(din*64) | b_base(64) | b_agg(64)
__global__ __launch_bounds__(256) void k_prep(const float* __restrict__ Wn, const float* __restrict__ Wr,
                                              const float* __restrict__ b, const float* __restrict__ stats,
                                              const float* __restrict__ g, const float* __restrict__ be,
                                              float* __restrict__ wbuf, int din){
  __shared__ float sc[64], sh[64];
  int t = threadIdx.x;
  if (t < 64){
    float a = 1.0f, s0 = 0.0f;
    if (stats){
      float m = stats[t] * (1.0f/NN);
      float v = stats[64+t] * (1.0f/NN) - m*m;
      a  = g[t] * rsqrtf(v + EPSV);
      s0 = be[t] - m*a;
    }
    sc[t] = a; sh[t] = s0;
  }
  __syncthreads();
  for (int i = t; i < din*64; i += 256){
    int k = i >> 6;
    wbuf[i]          = sc[k]*Wn[i];
    wbuf[din*64 + i] = sc[k]*Wr[i];
  }
  if (t < 64){
    float accB = b ? b[t] : 0.0f;
    float accN = 0.0f;
    for (int k=0;k<din;k++){
      accB += sh[k]*Wr[k*64+t];
      accN += sh[k]*Wn[k*64+t];
    }
    wbuf[2*din*64 + t]      = accB;
    wbuf[2*din*64 + 64 + t] = accN;
  }
}

// ---------------- conv GEMM: out = 1{deg>0}(invdeg*agg@Wn' + b_agg) + x@Wr' + b_base ----------------
template<int DIN, int ACT, bool STATS>
__global__ __launch_bounds__(256) void k_gemm_conv(const float* __restrict__ agg, const float* __restrict__ x,
                                                   const float* __restrict__ invdeg, const float* __restrict__ wbuf,
                                                   float* __restrict__ out, float* __restrict__ stats){
  const int lane  = threadIdx.x & 63;
  const int wave  = blockIdx.x*4 + (threadIdx.x >> 6);
  const int nwav  = gridDim.x*4;
  float wn[DIN], wr[DIN];
  #pragma unroll
  for (int k=0;k<DIN;k++){
    wn[k] = wbuf[k*64+lane];
    wr[k] = wbuf[(DIN+k)*64+lane];
  }
  const float bj0 = wbuf[2*DIN*64+lane];
  const float bj1 = wbuf[2*DIN*64+64+lane];
  float ls = 0.0f, lss = 0.0f;
  for (int n = wave; n < NN; n += nwav){
    const float* ar = agg + (size_t)n*DIN;
    const float* xr = x   + (size_t)n*DIN;
    float accA = 0.0f, accX = 0.0f;
    if constexpr ((DIN & 3) == 0){
      const float4* a4 = (const float4*)ar;
      const float4* x4 = (const float4*)xr;
      #pragma unroll
      for (int c=0;c<DIN/4;c++){
        float4 a = a4[c], b = x4[c];
        accA = fmaf(a.x, wn[4*c+0], accA);
        accX = fmaf(b.x, wr[4*c+0], accX);
        accA = fmaf(a.y, wn[4*c+1], accA);
        accX = fmaf(b.y, wr[4*c+1], accX);
        accA = fmaf(a.z, wn[4*c+2], accA);
        accX = fmaf(b.z, wr[4*c+2], accX);
        accA = fmaf(a.w, wn[4*c+3], accA);
        accX = fmaf(b.w, wr[4*c+3], accX);
      }
    } else {
      #pragma unroll
      for (int k=0;k<DIN;k++){
        accA = fmaf(ar[k], wn[k], accA);
        accX = fmaf(xr[k], wr[k], accX);
      }
    }
    float iv = invdeg[n];
    float aggterm = (iv > 0.0f) ? fmaf(accA, iv, bj1) : 0.0f;
    float z = accX + bj0 + aggterm;
    if (ACT == 1) z = z > 0.0f ? z : 0.01f*z;
    if (ACT == 2) z = fmaxf(z, 0.0f);
    out[(size_t)n*64 + lane] = z;
    if (STATS){ ls += z; lss = fmaf(z,z,lss); }
  }
  if (STATS){
    atomicAdd(&stats[lane], ls);
    atomicAdd(&stats[64+lane], lss);
  }
}

// ---------------- plain linear ----------------
template<int DOUT, bool STATS, bool BIAS>
__global__ __launch_bounds__(256) void k_gemm_lin(const float* __restrict__ x, const float* __restrict__ W,
                                                  const float* __restrict__ bias, float* __restrict__ out,
                                                  float* __restrict__ stats){
  const int lane = threadIdx.x & 63;
  const int wave = blockIdx.x*4 + (threadIdx.x >> 6);
  const int nwav = gridDim.x*4;
  if (DOUT < 64 && lane >= DOUT) return;
  float w[64];
  #pragma unroll
  for (int k=0;k<64;k++) w[k] = W[k*DOUT + lane];
  const float bj = BIAS ? bias[lane] : 0.0f;
  float ls = 0.0f, lss = 0.0f;
  for (int n = wave; n < NN; n += nwav){
    const float4* x4 = (const float4*)(x + (size_t)n*64);
    float acc0 = 0.0f, acc1 = 0.0f;
    #pragma unroll
    for (int c=0;c<8;c++){
      float4 v0 = x4[2*c], v1 = x4[2*c+1];
      acc0 = fmaf(v0.x, w[8*c+0], acc0);
      acc1 = fmaf(v1.x, w[8*c+4], acc1);
      acc0 = fmaf(v0.y, w[8*c+1], acc0);
      acc1 = fmaf(v1.y, w[8*c+5], acc1);
      acc0 = fmaf(v0.z, w[8*c+2], acc0);
      acc1 = fmaf(v1.z, w[8*c+6], acc1);
      acc0 = fmaf(v0.w, w[8*c+3], acc0);
      acc1 = fmaf(v1.w, w[8*c+7], acc1);
    }
    float z = acc0 + acc1 + bj;
    out[(size_t)n*DOUT + lane] = z;
    if (STATS){ ls += z; lss = fmaf(z,z,lss); }
  }
  if (STATS){ atomicAdd(&stats[lane], ls); atomicAdd(&stats[64+lane], lss); }
}

__global__ __launch_bounds__(256) void k_normrelu(float* __restrict__ h, const float* __restrict__ stats,
                                                  const float* __restrict__ g, const float* __restrict__ be){
  size_t idx = (size_t)blockIdx.x*256 + threadIdx.x;
  int f = (int)(idx & 63);
  float m = stats[f] * (1.0f/NN);
  float v = stats[64+f] * (1.0f/NN) - m*m;
  float a = g[f]*rsqrtf(v+EPSV);
  float b = be[f] - m*a;
  float z = h[idx];
  h[idx] = fmaxf(fmaf(a, z, b), 0.0f);
}

extern "C" void kernel_launch(void* const* d_in, const int* in_sizes, int n_in,
                              void* d_out, int out_size, void* d_ws, size_t ws_size,
                              hipStream_t stream){
  const float* x1  = (const float*)d_in[0];
  const int*   ei  = (const int*)d_in[1];
  const int* srcp = ei;
  const int* dstp = ei + EE;
  const float *Wn1=(const float*)d_in[2],  *Wr1=(const float*)d_in[3],  *b1=(const float*)d_in[4];
  const float *Wn2=(const float*)d_in[5],  *Wr2=(const float*)d_in[6],  *b2=(const float*)d_in[7];
  const float *Wn3=(const float*)d_in[8],  *Wr3=(const float*)d_in[9],  *b3=(const float*)d_in[10];
  const float *Wn4=(const float*)d_in[11], *Wr4=(const float*)d_in[12], *b4=(const float*)d_in[13];
  const float *g1=(const float*)d_in[14], *be1=(const float*)d_in[15];
  const float *g2=(const float*)d_in[16], *be2=(const float*)d_in[17];
  const float *g3=(const float*)d_in[18], *be3=(const float*)d_in[19];
  const float *Wm0=(const float*)d_in[20], *gm0=(const float*)d_in[21], *bem0=(const float*)d_in[22];
  const float *Wm1=(const float*)d_in[23], *gm1=(const float*)d_in[24], *bem1=(const float*)d_in[25];
  const float *Wm2=(const float*)d_in[26], *bm2=(const float*)d_in[27];
  float* out = (float*)d_out;

  char* ws = (char*)d_ws;
  int*   cnt     = (int*)(ws);                        // N ints
  int*   row_ptr = (int*)(ws + (1ull<<20));           // N ints
  int*   cursor  = (int*)(ws + (2ull<<20));           // N ints
  int*   pre     = (int*)(ws + (3ull<<20));           // N ints
  int*   blksum  = (int*)(ws + (4ull<<20));           // NB_SCAN ints
  float* invdeg  = (float*)(ws + (5ull<<20));         // N floats
  int*   adj     = (int*)(ws + (6ull<<20));           // E ints (4.8 MB)
  float* agg     = (float*)(ws + (12ull<<20));        // N*64 floats (30.7 MB)
  float* hA      = (float*)(ws + (43ull<<20));
  float* hB      = (float*)(ws + (74ull<<20));
  float* stats   = (float*)(ws + (105ull<<20));       // 5 x 128 floats
  float* wbuf    = (float*)(ws + (105ull<<20) + 8192);

  // ---- CSR build
  hipMemsetAsync(cnt, 0, NN*sizeof(int), stream);
  hipMemsetAsync(stats, 0, 5*128*sizeof(float), stream);
  k_count<<<(EE+255)/256,256,0,stream>>>(dstp, cnt);
  k_scan1<<<NB_SCAN,256,0,stream>>>(cnt, pre, blksum);
  k_scan2<<<1,512,0,stream>>>(blksum);
  k_scan3<<<NB_SCAN,256,0,stream>>>(pre, blksum, cnt, row_ptr, cursor, invdeg);
  k_fill<<<(EE+255)/256,256,0,stream>>>(srcp, dstp, cursor, adj);

  // ---- conv1: gather x1 (d=14), lrelu, stats->S1
  k_gather14<<<2048,256,0,stream>>>(x1, row_ptr, cnt, adj, agg);
  k_prep<<<1,256,0,stream>>>(Wn1,Wr1,b1,nullptr,nullptr,nullptr,wbuf,14);
  k_gemm_conv<14,1,true><<<2048,256,0,stream>>>(agg,x1,invdeg,wbuf,hA,stats);

  // ---- conv2: BN1 folded; gather raw hA
  k_gather64<<<2048,256,0,stream>>>(hA, row_ptr, cnt, adj, agg);
  k_prep<<<1,256,0,stream>>>(Wn2,Wr2,b2,stats,g1,be1,wbuf,64);
  k_gemm_conv<64,1,true><<<2048,256,0,stream>>>(agg,hA,invdeg,wbuf,hB,stats+128);

  // ---- conv3: BN2 folded; relu
  k_gather64<<<2048,256,0,stream>>>(hB, row_ptr, cnt, adj, agg);
  k_prep<<<1,256,0,stream>>>(Wn3,Wr3,b3,stats+128,g2,be2,wbuf,64);
  k_gemm_conv<64,2,true><<<2048,256,0,stream>>>(agg,hB,invdeg,wbuf,hA,stats+256);

  // ---- conv4: BN3 folded; no act
  k_gather64<<<2048,256,0,stream>>>(hA, row_ptr, cnt, adj, agg);
  k_prep<<<1,256,0,stream>>>(Wn4,Wr4,b4,stats+256,g3,be3,wbuf,64);
  k_gemm_conv<64,0,false><<<2048,256,0,stream>>>(agg,hA,invdeg,wbuf,hB,nullptr);

  // ---- MLP head
  k_gemm_lin<64,true,false><<<2048,256,0,stream>>>(hB,Wm0,nullptr,hA,stats+384);
  k_normrelu<<<(NN*64)/256,256,0,stream>>>(hA,stats+384,gm0,bem0);
  k_gemm_lin<64,true,false><<<2048,256,0,stream>>>(hA,Wm1,nullptr,hB,stats+512);
  k_normrelu<<<(NN*64)/256,256,0,stream>>>(hB,stats+512,gm1,bem1);
  k_gemm_lin<21,false,true><<<2048,256,0,stream>>>(hB,Wm2,bm2,out,nullptr);
}